// Round 9
// baseline (146.627 us; speedup 1.0000x reference)
//
#include <hip/hip_runtime.h>

#define WIN 33
#define WIDTH 128
#define MPTS 64
#define NN 2048
#define MM 2048
#define DD 64
#define NQ 2080   // N + 2L

typedef __bf16 bf16x8 __attribute__((ext_vector_type(8)));
typedef float f32x4 __attribute__((ext_vector_type(4)));

__device__ __forceinline__ unsigned short f2bf(float x) {
  union { float f; unsigned int u; } v; v.f = x;
  unsigned int r = v.u + 0x7FFFu + ((v.u >> 16) & 1u);  // RNE
  return (unsigned short)(r >> 16);
}
__device__ __forceinline__ float sigf(float x) { return 1.0f / (1.0f + __expf(-x)); }

// async global->LDS, 16B per lane, fire-and-forget (drained by vmcnt at barrier)
__device__ __forceinline__ void gll16(const unsigned short* g, unsigned short* l) {
  __builtin_amdgcn_global_load_lds(
      (const __attribute__((address_space(1))) unsigned int*)g,
      (__attribute__((address_space(3))) unsigned int*)l, 16, 0, 0);
}

__device__ __forceinline__ bf16x8 cvt8(const float4& a, const float4& b) {
  union { bf16x8 v; unsigned short s[8]; } u;
  u.s[0] = f2bf(a.x); u.s[1] = f2bf(a.y); u.s[2] = f2bf(a.z); u.s[3] = f2bf(a.w);
  u.s[4] = f2bf(b.x); u.s[5] = f2bf(b.y); u.s[6] = f2bf(b.z); u.s[7] = f2bf(b.w);
  return u.v;
}

// ------------- fused prep: MLP (bid<33) + transpose (bid>=33) + out-zero ---
// R9: MLP branch = 4 phases / 3 barriers (was 11 barriers). Weights go
// DIRECTLY global->registers (f32->bf16 in-reg): each wave's A-fragments are
// wave-private rows, so LDS staging shared nothing and cost 2 barriers +
// LDS round-trip per stage at 1 wave/SIMD. All weight loads issue >=1 phase
// ahead (w0,w1 in A; w2 in B). Final layer writes sigmoid straight to u1bf.
// Barriers now only guard the actA/actB ping-pong.
__global__ __launch_bounds__(256) void k_prep(const float* __restrict__ xi,
                                              unsigned short* __restrict__ xiT,
                                              const float* __restrict__ u,
                                              const float* __restrict__ w0,
                                              const float* __restrict__ b0,
                                              const float* __restrict__ w,
                                              const float* __restrict__ bias,
                                              unsigned short* __restrict__ u1bf,
                                              float* __restrict__ out) {
  extern __shared__ char smem[];
  int bid = blockIdx.x;
  int tid = threadIdx.x;

  if (bid < 33) {
    // ---------------- MLP branch ----------------
    constexpr int AS = 136;
    float* biass = (float*)smem;                              // 3*128*4 = 1,536 B
    unsigned short* actA = (unsigned short*)(smem + 1536);    // 17,408 B
    unsigned short* actB = (unsigned short*)(smem + 18944);   // 17,408 B
    int j = bid;
    int wv = tid >> 6, lane = tid & 63, l15 = lane & 15, l4 = lane >> 4;
    int colb = l4 << 3;                    // this lane's 8-float column base

    const float* wb0 = w + (size_t)j * 16384;            // layer-1 weights
    const float* wb1 = w + (size_t)(WIN + j) * 16384;    // layer-2 weights

    float4 wr0[8], wr1[16], wr2[16];

    // ---- Phase A: stage u -> actA; issue w0 + w1 loads; all biases
    {
      float4 ureg[4];
#pragma unroll
      for (int r = 0; r < 4; ++r) {
        int c = tid + (r << 8);
        ureg[r] = *(const float4*)&u[(size_t)(c >> 4) * DD + ((c & 15) << 2)];
      }
#pragma unroll
      for (int s = 0; s < 2; ++s)
#pragma unroll
        for (int t = 0; t < 2; ++t) {      // w0: [33][128][64]
          int row = wv * 32 + s * 16 + l15, col = (t << 5) + colb;
          const float* p = &w0[((size_t)j * 128 + row) * 64 + col];
          wr0[(s * 2 + t) * 2 + 0] = *(const float4*)p;
          wr0[(s * 2 + t) * 2 + 1] = *(const float4*)(p + 4);
        }
#pragma unroll
      for (int s = 0; s < 2; ++s)
#pragma unroll
        for (int t = 0; t < 4; ++t) {      // w (layer1): [128][128]
          int row = wv * 32 + s * 16 + l15, col = (t << 5) + colb;
          const float* p = &wb0[(size_t)row * 128 + col];
          wr1[(s * 4 + t) * 2 + 0] = *(const float4*)p;
          wr1[(s * 4 + t) * 2 + 1] = *(const float4*)(p + 4);
        }
      if (tid < 128) {
        biass[tid]       = b0[j * 128 + tid];
        biass[128 + tid] = bias[(size_t)j * 128 + tid];
        biass[256 + tid] = bias[(size_t)(WIN + j) * 128 + tid];
      }
#pragma unroll
      for (int r = 0; r < 4; ++r) {
        int c = tid + (r << 8);
        float4 v = ureg[r];
        ushort4 h; h.x = f2bf(v.x); h.y = f2bf(v.y); h.z = f2bf(v.z); h.w = f2bf(v.w);
        *(ushort4*)&actA[(c >> 4) * AS + ((c & 15) << 2)] = h;
      }
    }
    __syncthreads();                       // barrier 1: actA + biases ready

    // ---- Phase B: issue w2; compute L0 (K=64); sig -> actB
#pragma unroll
    for (int s = 0; s < 2; ++s)
#pragma unroll
      for (int t = 0; t < 4; ++t) {        // w (layer2): [128][128]
        int row = wv * 32 + s * 16 + l15, col = (t << 5) + colb;
        const float* p = &wb1[(size_t)row * 128 + col];
        wr2[(s * 4 + t) * 2 + 0] = *(const float4*)p;
        wr2[(s * 4 + t) * 2 + 1] = *(const float4*)(p + 4);
      }
    {
      f32x4 acc[2][4] = {};
#pragma unroll
      for (int t = 0; t < 2; ++t) {
        int col = (t << 5) + colb;
        bf16x8 a[2], b[4];
#pragma unroll
        for (int s = 0; s < 2; ++s)
          a[s] = cvt8(wr0[(s * 2 + t) * 2], wr0[(s * 2 + t) * 2 + 1]);
#pragma unroll
        for (int q = 0; q < 4; ++q)
          b[q] = *(const bf16x8*)&actA[(q * 16 + l15) * AS + col];
#pragma unroll
        for (int s = 0; s < 2; ++s)
#pragma unroll
          for (int q = 0; q < 4; ++q)
            acc[s][q] = __builtin_amdgcn_mfma_f32_16x16x32_bf16(a[s], b[q], acc[s][q], 0, 0, 0);
      }
#pragma unroll
      for (int s = 0; s < 2; ++s)
#pragma unroll
        for (int q = 0; q < 4; ++q) {
          int p = q * 16 + l15;
          int k0 = wv * 32 + s * 16 + (l4 << 2);
          ushort4 st;
          st.x = f2bf(sigf(acc[s][q][0] + biass[k0 + 0]));
          st.y = f2bf(sigf(acc[s][q][1] + biass[k0 + 1]));
          st.z = f2bf(sigf(acc[s][q][2] + biass[k0 + 2]));
          st.w = f2bf(sigf(acc[s][q][3] + biass[k0 + 3]));
          *(ushort4*)&actB[p * AS + k0] = st;
        }
    }
    __syncthreads();                       // barrier 2: actB ready

    // ---- Phase C: compute L1 (K=128); sig -> actA
    {
      f32x4 acc[2][4] = {};
#pragma unroll
      for (int t = 0; t < 4; ++t) {
        int col = (t << 5) + colb;
        bf16x8 a[2], b[4];
#pragma unroll
        for (int s = 0; s < 2; ++s)
          a[s] = cvt8(wr1[(s * 4 + t) * 2], wr1[(s * 4 + t) * 2 + 1]);
#pragma unroll
        for (int q = 0; q < 4; ++q)
          b[q] = *(const bf16x8*)&actB[(q * 16 + l15) * AS + col];
#pragma unroll
        for (int s = 0; s < 2; ++s)
#pragma unroll
          for (int q = 0; q < 4; ++q)
            acc[s][q] = __builtin_amdgcn_mfma_f32_16x16x32_bf16(a[s], b[q], acc[s][q], 0, 0, 0);
      }
#pragma unroll
      for (int s = 0; s < 2; ++s)
#pragma unroll
        for (int q = 0; q < 4; ++q) {
          int p = q * 16 + l15;
          int k0 = wv * 32 + s * 16 + (l4 << 2);
          ushort4 st;
          st.x = f2bf(sigf(acc[s][q][0] + biass[128 + k0 + 0]));
          st.y = f2bf(sigf(acc[s][q][1] + biass[128 + k0 + 1]));
          st.z = f2bf(sigf(acc[s][q][2] + biass[128 + k0 + 2]));
          st.w = f2bf(sigf(acc[s][q][3] + biass[128 + k0 + 3]));
          *(ushort4*)&actA[p * AS + k0] = st;
        }
    }
    __syncthreads();                       // barrier 3: actA ready

    // ---- Phase D: compute L2 (K=128); sig -> u1bf (global, no LDS trip)
    {
      f32x4 acc[2][4] = {};
#pragma unroll
      for (int t = 0; t < 4; ++t) {
        int col = (t << 5) + colb;
        bf16x8 a[2], b[4];
#pragma unroll
        for (int s = 0; s < 2; ++s)
          a[s] = cvt8(wr2[(s * 4 + t) * 2], wr2[(s * 4 + t) * 2 + 1]);
#pragma unroll
        for (int q = 0; q < 4; ++q)
          b[q] = *(const bf16x8*)&actA[(q * 16 + l15) * AS + col];
#pragma unroll
        for (int s = 0; s < 2; ++s)
#pragma unroll
          for (int q = 0; q < 4; ++q)
            acc[s][q] = __builtin_amdgcn_mfma_f32_16x16x32_bf16(a[s], b[q], acc[s][q], 0, 0, 0);
      }
#pragma unroll
      for (int s = 0; s < 2; ++s)
#pragma unroll
        for (int q = 0; q < 4; ++q) {
          int p = q * 16 + l15;
          int k0 = wv * 32 + s * 16 + (l4 << 2);
          ushort4 st;
          st.x = f2bf(sigf(acc[s][q][0] + biass[256 + k0 + 0]));
          st.y = f2bf(sigf(acc[s][q][1] + biass[256 + k0 + 1]));
          st.z = f2bf(sigf(acc[s][q][2] + biass[256 + k0 + 2]));
          st.w = f2bf(sigf(acc[s][q][3] + biass[256 + k0 + 3]));
          *(ushort4*)&u1bf[((size_t)j * MPTS + p) * WIDTH + k0] = st;
        }
    }
  } else {
    // ---------------- transpose branch ----------------
    float* ts = (float*)smem;                // 64*37*4 = 9,472 B
    int t = bid - 33;                        // [0, 2080)
    if (t < 512 && tid < 64) {               // zero out (512 x 1KB = 512KB)
      float4 z = {0.f, 0.f, 0.f, 0.f};
      *(float4*)&out[((size_t)t << 8) + (tid << 2)] = z;
    }
    int qt = t % 65, mt = t / 65;
    int qb = qt * 32;                        // 65 tiles over NQ=2080
    int mb = mt * 64;                        // 32 tiles over M=2048
#pragma unroll
    for (int c = tid; c < 512; c += 256) {   // 64 rows x 8 float4
      int row = c >> 3, c8 = c & 7;
      float4 v = *(const float4*)&xi[(size_t)(mb + row) * NQ + qb + (c8 << 2)];
      ts[row * 37 + (c8 << 2) + 0] = v.x;
      ts[row * 37 + (c8 << 2) + 1] = v.y;
      ts[row * 37 + (c8 << 2) + 2] = v.z;
      ts[row * 37 + (c8 << 2) + 3] = v.w;
    }
    __syncthreads();
#pragma unroll
    for (int c = tid; c < 512; c += 256) {   // 32 q-rows x 16 m-quads
      int r = c >> 4, mq = c & 15;
      ushort4 h;
      h.x = f2bf(ts[(mq * 4 + 0) * 37 + r]);
      h.y = f2bf(ts[(mq * 4 + 1) * 37 + r]);
      h.z = f2bf(ts[(mq * 4 + 2) * 37 + r]);
      h.w = f2bf(ts[(mq * 4 + 3) * 37 + r]);
      *(ushort4*)&xiT[((size_t)mt * NQ + (qb + r)) * 64 + (mq << 2)] = h;
    }
  }
}

// ------------- phase B: Gt2 in k_conv staging order -----------------------
// Gt2[region = mp*2+half][j=33][g=4][p=64][8m], region = 67,584 shorts.
__global__ __launch_bounds__(256) void k_final(const float* __restrict__ wf,
                                               const float* __restrict__ bfin,
                                               const unsigned short* __restrict__ u1bf,
                                               unsigned short* __restrict__ Gt2) {
  constexpr int KP = 136;
  __shared__ unsigned short As[64 * KP];
  __shared__ unsigned short Bs[64 * KP];
  __shared__ float bfs[64];
  int bid = blockIdx.x;                    // 33*32
  int j = bid >> 5;
  int m0 = (bid & 31) << 6;
#pragma unroll
  for (int c = threadIdx.x; c < 64 * 32; c += 256) {
    int row = c >> 5, f4 = c & 31;
    float4 v = *(const float4*)(wf + ((size_t)(m0 + row) * WIN + j) * WIDTH + (f4 << 2));
    ushort4 h;
    h.x = f2bf(v.x); h.y = f2bf(v.y); h.z = f2bf(v.z); h.w = f2bf(v.w);
    *(ushort4*)(&As[row * KP + (f4 << 2)]) = h;
  }
#pragma unroll
  for (int c = threadIdx.x; c < 64 * 16; c += 256) {
    int p = c >> 4, ch = c & 15;
    uint4 v = *(const uint4*)(u1bf + (size_t)(j * MPTS + p) * WIDTH + (ch << 3));
    *(uint4*)(&Bs[p * KP + (ch << 3)]) = v;
  }
  if (threadIdx.x < 64) bfs[threadIdx.x] = bfin[(size_t)(m0 + threadIdx.x) * WIN + j];
  __syncthreads();
  int wv = threadIdx.x >> 6, lane = threadIdx.x & 63;
  int l15 = lane & 15, l4 = lane >> 4;
  f32x4 acc[4] = {};
#pragma unroll
  for (int t = 0; t < 4; ++t) {
    int col = (t << 5) + (l4 << 3);
    bf16x8 a = *(const bf16x8*)(&As[(wv * 16 + l15) * KP + col]);
#pragma unroll
    for (int q = 0; q < 4; ++q) {
      bf16x8 bb = *(const bf16x8*)(&Bs[(q * 16 + l15) * KP + col]);
      acc[q] = __builtin_amdgcn_mfma_f32_16x16x32_bf16(a, bb, acc[q], 0, 0, 0);
    }
  }
  // m_local = wv*16 + l4*4 + i  ->  half = wv>>1, g = (wv&1)*2 + (l4>>1),
  // m8 = (l4&1)*4. Stores hit 2x256B contiguous runs per wave instruction.
  size_t region = (size_t)((bid & 31) << 1) + (wv >> 1);
  int g = ((wv & 1) << 1) + (l4 >> 1);
  int m8 = (l4 & 1) << 2;
  int mb = wv * 16 + (l4 << 2);
#pragma unroll
  for (int q = 0; q < 4; ++q) {
    int p = q * 16 + l15;
    float z0 = acc[q][0] + bfs[mb + 0];
    float z1 = acc[q][1] + bfs[mb + 1];
    float z2 = acc[q][2] + bfs[mb + 2];
    float z3 = acc[q][3] + bfs[mb + 3];
    ushort4 st;
    st.x = f2bf(sigf(z0)); st.y = f2bf(sigf(z1));
    st.z = f2bf(sigf(z2)); st.w = f2bf(sigf(z3));
    *(ushort4*)(&Gt2[region * 67584 + ((size_t)(j * 4 + g) * 64 + p) * 8 + m8]) = st;
  }
}

// ------------- phase C: out[n,p] += sum_{j,m} xiT[n+j,m] * Gt2[j,p,m] ------
// Exact R5 structure (best measured). Rotated 2-phase pipeline, Bs
// double-buffered, next phase's global_load_lds issued right after the
// barrier, before compute. No setprio (R7: neutral).
__global__ __launch_bounds__(256) void k_conv(const unsigned short* __restrict__ xiT,
                                              const unsigned short* __restrict__ Gt2,
                                              float* __restrict__ out) {
  extern __shared__ unsigned short lds[];
  unsigned short* As = lds;                // [160][64] swizzled = 20,480 B
  int bid = blockIdx.x;
  int mp = bid & 31;                       // bid%8 == mp%8 -> same-B blocks share an XCD
  int n0 = (bid >> 5) << 7;                // 16 n-tiles of 128
  int tid = threadIdx.x;
  int wv = tid >> 6, lane = tid & 63, l15 = lane & 15, l4 = lane >> 4;

  // ---- stage A once: contiguous 1KB per instr; XOR permute (c ^= row&7)
  const unsigned short* Abase = xiT + (size_t)mp * (NQ * 64) + (size_t)n0 * 64;
#pragma unroll
  for (int k = 0; k < 5; ++k) {
    int instr = wv * 5 + k;                // 20 wave-instructions
    int s = (instr << 6) + lane;
    int row = s >> 3;
    int c = (s & 7) ^ (row & 7);
    gll16(Abase + (size_t)row * 64 + (c << 3), As + (instr << 9));
  }

  // phase tables: t = half*5 + p
  constexpr int JBT[10]  = {0, 7, 14, 21, 28, 0, 7, 14, 21, 28};
  constexpr int CNTT[10] = {7, 7, 7, 7, 5, 7, 7, 7, 7, 5};
  constexpr int HFT[10]  = {0, 0, 0, 0, 0, 1, 1, 1, 1, 1};

  const unsigned short* Rb0 = Gt2 + (size_t)(mp << 1) * 67584;        // half 0
  const unsigned short* Rb1 = Gt2 + (size_t)((mp << 1) + 1) * 67584;  // half 1

  // ---- prologue: issue B(phase 0) into buf0
  {
    const unsigned short* Bb = Rb0;        // jb=0
#pragma unroll
    for (int k = 0; k < 7; ++k) {
      int instr = wv * 7 + k;
      gll16(Bb + (((instr << 6) + lane) << 3), lds + 10240 + (instr << 9));
    }
  }

  f32x4 acc[2][4] = {};
#pragma unroll
  for (int t = 0; t < 10; ++t) {
    __syncthreads();   // drains own vmcnt(0): A + B(t) ready; all waves done
                       // reading the buffer about to be overwritten.
    if (t < 9) {       // issue B(t+1) into buf[(t+1)&1]; lands during compute(t)
      const int jbn = JBT[t + 1], cntn = CNTT[t + 1];
      const unsigned short* Bb =
          (HFT[t + 1] ? Rb1 : Rb0) + ((size_t)jbn << 11);
      unsigned short* Bst = lds + 10240 + ((t + 1) & 1) * 14336;
#pragma unroll
      for (int k = 0; k < cntn; ++k) {
        int instr = wv * cntn + k;
        gll16(Bb + (((instr << 6) + lane) << 3), Bst + (instr << 9));
      }
    }
    // ---- compute phase t from buf[t&1]
    {
      const int jb = JBT[t], cnt = CNTT[t], h4 = HFT[t] << 2;
      const unsigned short* Bs = lds + 10240 + (t & 1) * 14336;
      bf16x8 a[2], b[4];
#pragma unroll
      for (int s = 0; s < 2; ++s) {
        int row = wv * 32 + s * 16 + l15 + jb;
        a[s] = *(const bf16x8*)&As[row * 64 + (((h4 | l4) ^ (row & 7)) << 3)];
      }
#pragma unroll
      for (int q = 0; q < 4; ++q) {
        int slot = (l4 << 6) + (q << 4) + l15;
        b[q] = *(const bf16x8*)&Bs[slot << 3];
      }
#pragma unroll
      for (int jj = 0; jj < cnt; ++jj) {
        bf16x8 an[2], bn[4];
        if (jj < cnt - 1) {                // prefetch j+1 while computing j
#pragma unroll
          for (int s = 0; s < 2; ++s) {
            int row = wv * 32 + s * 16 + l15 + jb + jj + 1;
            an[s] = *(const bf16x8*)&As[row * 64 + (((h4 | l4) ^ (row & 7)) << 3)];
          }
#pragma unroll
          for (int q = 0; q < 4; ++q) {
            int slot = ((((jj + 1) << 2) + l4) << 6) + (q << 4) + l15;
            bn[q] = *(const bf16x8*)&Bs[slot << 3];
          }
        }
#pragma unroll
        for (int s = 0; s < 2; ++s)
#pragma unroll
          for (int q = 0; q < 4; ++q)
            acc[s][q] = __builtin_amdgcn_mfma_f32_16x16x32_bf16(a[s], b[q], acc[s][q], 0, 0, 0);
#pragma unroll
        for (int s = 0; s < 2; ++s) a[s] = an[s];
#pragma unroll
        for (int q = 0; q < 4; ++q) b[q] = bn[q];
      }
    }
  }
#pragma unroll
  for (int s = 0; s < 2; ++s)
#pragma unroll
    for (int q = 0; q < 4; ++q) {
      int nr = n0 + wv * 32 + s * 16 + (l4 << 2);
      int p = q * 16 + l15;
#pragma unroll
      for (int i = 0; i < 4; ++i)
        atomicAdd(&out[(size_t)(nr + i) * MPTS + p], acc[s][q][i]);
    }
}

extern "C" void kernel_launch(void* const* d_in, const int* in_sizes, int n_in,
                              void* d_out, int out_size, void* d_ws, size_t ws_size,
                              hipStream_t stream) {
  const float* u    = (const float*)d_in[0];  // [64,64]
  const float* w0   = (const float*)d_in[1];  // [33,128,64]
  const float* b0   = (const float*)d_in[2];  // [33,128,1]
  const float* w    = (const float*)d_in[3];  // [2,33,128,128]
  const float* bias = (const float*)d_in[4];  // [2,33,128,1]
  const float* wf   = (const float*)d_in[5];  // [2048,33,128]
  const float* bfin = (const float*)d_in[6];  // [2048,33,1]
  const float* xi   = (const float*)d_in[7];  // [2048,2080]
  float* out = (float*)d_out;                 // [2048,64]
  char* ws = (char*)d_ws;
  unsigned short* xiT  = (unsigned short*)(ws);             // 8,519,680 B
  unsigned short* Gt2  = (unsigned short*)(ws + 8519680);   // 8,650,752 B
  unsigned short* u1bf = (unsigned short*)(ws + 17170432);  // 540,672 B

  hipFuncSetAttribute(reinterpret_cast<const void*>(&k_prep),
                      hipFuncAttributeMaxDynamicSharedMemorySize, 36352);
  hipFuncSetAttribute(reinterpret_cast<const void*>(&k_conv),
                      hipFuncAttributeMaxDynamicSharedMemorySize, 77824);

  k_prep<<<2113, 256, 36352, stream>>>(xi, xiT, u, w0, b0, w, bias, u1bf, out);
  k_final<<<33 * 32, 256, 0, stream>>>(wf, bfin, u1bf, Gt2);
  k_conv<<<512, 256, 77824, stream>>>(xiT, Gt2, out);
}

// Round 10
// 145.484 us; speedup vs baseline: 1.0079x; 1.0079x over previous
//
#include <hip/hip_runtime.h>

#define WIN 33
#define WIDTH 128
#define MPTS 64
#define NN 2048
#define MM 2048
#define DD 64
#define NQ 2080   // N + 2L

typedef __bf16 bf16x8 __attribute__((ext_vector_type(8)));
typedef float f32x4 __attribute__((ext_vector_type(4)));

__device__ __forceinline__ unsigned short f2bf(float x) {
  union { float f; unsigned int u; } v; v.f = x;
  unsigned int r = v.u + 0x7FFFu + ((v.u >> 16) & 1u);  // RNE
  return (unsigned short)(r >> 16);
}
__device__ __forceinline__ float sigf(float x) { return 1.0f / (1.0f + __expf(-x)); }

// async global->LDS, 16B per lane, fire-and-forget (tracked by vmcnt)
__device__ __forceinline__ void gll16(const unsigned short* g, unsigned short* l) {
  __builtin_amdgcn_global_load_lds(
      (const __attribute__((address_space(1))) unsigned int*)g,
      (__attribute__((address_space(3))) unsigned int*)l, 16, 0, 0);
}

__device__ __forceinline__ bf16x8 cvt8(const float4& a, const float4& b) {
  union { bf16x8 v; unsigned short s[8]; } u;
  u.s[0] = f2bf(a.x); u.s[1] = f2bf(a.y); u.s[2] = f2bf(a.z); u.s[3] = f2bf(a.w);
  u.s[4] = f2bf(b.x); u.s[5] = f2bf(b.y); u.s[6] = f2bf(b.z); u.s[7] = f2bf(b.w);
  return u.v;
}

// ------------- fused prep: MLP (bid<33) + transpose (bid>=33) + out-zero ---
// R9 structure kept: MLP = 4 phases / 3 barriers, weights direct
// global->registers (wave-private fragments), final layer writes straight
// to u1bf. Transpose branch unchanged.
__global__ __launch_bounds__(256) void k_prep(const float* __restrict__ xi,
                                              unsigned short* __restrict__ xiT,
                                              const float* __restrict__ u,
                                              const float* __restrict__ w0,
                                              const float* __restrict__ b0,
                                              const float* __restrict__ w,
                                              const float* __restrict__ bias,
                                              unsigned short* __restrict__ u1bf,
                                              float* __restrict__ out) {
  extern __shared__ char smem[];
  int bid = blockIdx.x;
  int tid = threadIdx.x;

  if (bid < 33) {
    // ---------------- MLP branch ----------------
    constexpr int AS = 136;
    float* biass = (float*)smem;                              // 3*128*4 = 1,536 B
    unsigned short* actA = (unsigned short*)(smem + 1536);    // 17,408 B
    unsigned short* actB = (unsigned short*)(smem + 18944);   // 17,408 B
    int j = bid;
    int wv = tid >> 6, lane = tid & 63, l15 = lane & 15, l4 = lane >> 4;
    int colb = l4 << 3;                    // this lane's 8-float column base

    const float* wb0 = w + (size_t)j * 16384;            // layer-1 weights
    const float* wb1 = w + (size_t)(WIN + j) * 16384;    // layer-2 weights

    float4 wr0[8], wr1[16], wr2[16];

    // ---- Phase A: stage u -> actA; issue w0 + w1 loads; all biases
    {
      float4 ureg[4];
#pragma unroll
      for (int r = 0; r < 4; ++r) {
        int c = tid + (r << 8);
        ureg[r] = *(const float4*)&u[(size_t)(c >> 4) * DD + ((c & 15) << 2)];
      }
#pragma unroll
      for (int s = 0; s < 2; ++s)
#pragma unroll
        for (int t = 0; t < 2; ++t) {      // w0: [33][128][64]
          int row = wv * 32 + s * 16 + l15, col = (t << 5) + colb;
          const float* p = &w0[((size_t)j * 128 + row) * 64 + col];
          wr0[(s * 2 + t) * 2 + 0] = *(const float4*)p;
          wr0[(s * 2 + t) * 2 + 1] = *(const float4*)(p + 4);
        }
#pragma unroll
      for (int s = 0; s < 2; ++s)
#pragma unroll
        for (int t = 0; t < 4; ++t) {      // w (layer1): [128][128]
          int row = wv * 32 + s * 16 + l15, col = (t << 5) + colb;
          const float* p = &wb0[(size_t)row * 128 + col];
          wr1[(s * 4 + t) * 2 + 0] = *(const float4*)p;
          wr1[(s * 4 + t) * 2 + 1] = *(const float4*)(p + 4);
        }
      if (tid < 128) {
        biass[tid]       = b0[j * 128 + tid];
        biass[128 + tid] = bias[(size_t)j * 128 + tid];
        biass[256 + tid] = bias[(size_t)(WIN + j) * 128 + tid];
      }
#pragma unroll
      for (int r = 0; r < 4; ++r) {
        int c = tid + (r << 8);
        float4 v = ureg[r];
        ushort4 h; h.x = f2bf(v.x); h.y = f2bf(v.y); h.z = f2bf(v.z); h.w = f2bf(v.w);
        *(ushort4*)&actA[(c >> 4) * AS + ((c & 15) << 2)] = h;
      }
    }
    __syncthreads();                       // barrier 1: actA + biases ready

    // ---- Phase B: issue w2; compute L0 (K=64); sig -> actB
#pragma unroll
    for (int s = 0; s < 2; ++s)
#pragma unroll
      for (int t = 0; t < 4; ++t) {        // w (layer2): [128][128]
        int row = wv * 32 + s * 16 + l15, col = (t << 5) + colb;
        const float* p = &wb1[(size_t)row * 128 + col];
        wr2[(s * 4 + t) * 2 + 0] = *(const float4*)p;
        wr2[(s * 4 + t) * 2 + 1] = *(const float4*)(p + 4);
      }
    {
      f32x4 acc[2][4] = {};
#pragma unroll
      for (int t = 0; t < 2; ++t) {
        int col = (t << 5) + colb;
        bf16x8 a[2], b[4];
#pragma unroll
        for (int s = 0; s < 2; ++s)
          a[s] = cvt8(wr0[(s * 2 + t) * 2], wr0[(s * 2 + t) * 2 + 1]);
#pragma unroll
        for (int q = 0; q < 4; ++q)
          b[q] = *(const bf16x8*)&actA[(q * 16 + l15) * AS + col];
#pragma unroll
        for (int s = 0; s < 2; ++s)
#pragma unroll
          for (int q = 0; q < 4; ++q)
            acc[s][q] = __builtin_amdgcn_mfma_f32_16x16x32_bf16(a[s], b[q], acc[s][q], 0, 0, 0);
      }
#pragma unroll
      for (int s = 0; s < 2; ++s)
#pragma unroll
        for (int q = 0; q < 4; ++q) {
          int p = q * 16 + l15;
          int k0 = wv * 32 + s * 16 + (l4 << 2);
          ushort4 st;
          st.x = f2bf(sigf(acc[s][q][0] + biass[k0 + 0]));
          st.y = f2bf(sigf(acc[s][q][1] + biass[k0 + 1]));
          st.z = f2bf(sigf(acc[s][q][2] + biass[k0 + 2]));
          st.w = f2bf(sigf(acc[s][q][3] + biass[k0 + 3]));
          *(ushort4*)&actB[p * AS + k0] = st;
        }
    }
    __syncthreads();                       // barrier 2: actB ready

    // ---- Phase C: compute L1 (K=128); sig -> actA
    {
      f32x4 acc[2][4] = {};
#pragma unroll
      for (int t = 0; t < 4; ++t) {
        int col = (t << 5) + colb;
        bf16x8 a[2], b[4];
#pragma unroll
        for (int s = 0; s < 2; ++s)
          a[s] = cvt8(wr1[(s * 4 + t) * 2], wr1[(s * 4 + t) * 2 + 1]);
#pragma unroll
        for (int q = 0; q < 4; ++q)
          b[q] = *(const bf16x8*)&actB[(q * 16 + l15) * AS + col];
#pragma unroll
        for (int s = 0; s < 2; ++s)
#pragma unroll
          for (int q = 0; q < 4; ++q)
            acc[s][q] = __builtin_amdgcn_mfma_f32_16x16x32_bf16(a[s], b[q], acc[s][q], 0, 0, 0);
      }
#pragma unroll
      for (int s = 0; s < 2; ++s)
#pragma unroll
        for (int q = 0; q < 4; ++q) {
          int p = q * 16 + l15;
          int k0 = wv * 32 + s * 16 + (l4 << 2);
          ushort4 st;
          st.x = f2bf(sigf(acc[s][q][0] + biass[128 + k0 + 0]));
          st.y = f2bf(sigf(acc[s][q][1] + biass[128 + k0 + 1]));
          st.z = f2bf(sigf(acc[s][q][2] + biass[128 + k0 + 2]));
          st.w = f2bf(sigf(acc[s][q][3] + biass[128 + k0 + 3]));
          *(ushort4*)&actA[p * AS + k0] = st;
        }
    }
    __syncthreads();                       // barrier 3: actA ready

    // ---- Phase D: compute L2 (K=128); sig -> u1bf (global, no LDS trip)
    {
      f32x4 acc[2][4] = {};
#pragma unroll
      for (int t = 0; t < 4; ++t) {
        int col = (t << 5) + colb;
        bf16x8 a[2], b[4];
#pragma unroll
        for (int s = 0; s < 2; ++s)
          a[s] = cvt8(wr2[(s * 4 + t) * 2], wr2[(s * 4 + t) * 2 + 1]);
#pragma unroll
        for (int q = 0; q < 4; ++q)
          b[q] = *(const bf16x8*)&actA[(q * 16 + l15) * AS + col];
#pragma unroll
        for (int s = 0; s < 2; ++s)
#pragma unroll
          for (int q = 0; q < 4; ++q)
            acc[s][q] = __builtin_amdgcn_mfma_f32_16x16x32_bf16(a[s], b[q], acc[s][q], 0, 0, 0);
      }
#pragma unroll
      for (int s = 0; s < 2; ++s)
#pragma unroll
        for (int q = 0; q < 4; ++q) {
          int p = q * 16 + l15;
          int k0 = wv * 32 + s * 16 + (l4 << 2);
          ushort4 st;
          st.x = f2bf(sigf(acc[s][q][0] + biass[256 + k0 + 0]));
          st.y = f2bf(sigf(acc[s][q][1] + biass[256 + k0 + 1]));
          st.z = f2bf(sigf(acc[s][q][2] + biass[256 + k0 + 2]));
          st.w = f2bf(sigf(acc[s][q][3] + biass[256 + k0 + 3]));
          *(ushort4*)&u1bf[((size_t)j * MPTS + p) * WIDTH + k0] = st;
        }
    }
  } else {
    // ---------------- transpose branch ----------------
    float* ts = (float*)smem;                // 64*37*4 = 9,472 B
    int t = bid - 33;                        // [0, 2080)
    if (t < 512 && tid < 64) {               // zero out (512 x 1KB = 512KB)
      float4 z = {0.f, 0.f, 0.f, 0.f};
      *(float4*)&out[((size_t)t << 8) + (tid << 2)] = z;
    }
    int qt = t % 65, mt = t / 65;
    int qb = qt * 32;                        // 65 tiles over NQ=2080
    int mb = mt * 64;                        // 32 tiles over M=2048
#pragma unroll
    for (int c = tid; c < 512; c += 256) {   // 64 rows x 8 float4
      int row = c >> 3, c8 = c & 7;
      float4 v = *(const float4*)&xi[(size_t)(mb + row) * NQ + qb + (c8 << 2)];
      ts[row * 37 + (c8 << 2) + 0] = v.x;
      ts[row * 37 + (c8 << 2) + 1] = v.y;
      ts[row * 37 + (c8 << 2) + 2] = v.z;
      ts[row * 37 + (c8 << 2) + 3] = v.w;
    }
    __syncthreads();
#pragma unroll
    for (int c = tid; c < 512; c += 256) {   // 32 q-rows x 16 m-quads
      int r = c >> 4, mq = c & 15;
      ushort4 h;
      h.x = f2bf(ts[(mq * 4 + 0) * 37 + r]);
      h.y = f2bf(ts[(mq * 4 + 1) * 37 + r]);
      h.z = f2bf(ts[(mq * 4 + 2) * 37 + r]);
      h.w = f2bf(ts[(mq * 4 + 3) * 37 + r]);
      *(ushort4*)&xiT[((size_t)mt * NQ + (qb + r)) * 64 + (mq << 2)] = h;
    }
  }
}

// ------------- phase B: Gt2 in k_conv staging order -----------------------
// Gt2[region = mp*2+half][j=33][g=4][p=64][8m], region = 67,584 shorts.
__global__ __launch_bounds__(256) void k_final(const float* __restrict__ wf,
                                               const float* __restrict__ bfin,
                                               const unsigned short* __restrict__ u1bf,
                                               unsigned short* __restrict__ Gt2) {
  constexpr int KP = 136;
  __shared__ unsigned short As[64 * KP];
  __shared__ unsigned short Bs[64 * KP];
  __shared__ float bfs[64];
  int bid = blockIdx.x;                    // 33*32
  int j = bid >> 5;
  int m0 = (bid & 31) << 6;
#pragma unroll
  for (int c = threadIdx.x; c < 64 * 32; c += 256) {
    int row = c >> 5, f4 = c & 31;
    float4 v = *(const float4*)(wf + ((size_t)(m0 + row) * WIN + j) * WIDTH + (f4 << 2));
    ushort4 h;
    h.x = f2bf(v.x); h.y = f2bf(v.y); h.z = f2bf(v.z); h.w = f2bf(v.w);
    *(ushort4*)(&As[row * KP + (f4 << 2)]) = h;
  }
#pragma unroll
  for (int c = threadIdx.x; c < 64 * 16; c += 256) {
    int p = c >> 4, ch = c & 15;
    uint4 v = *(const uint4*)(u1bf + (size_t)(j * MPTS + p) * WIDTH + (ch << 3));
    *(uint4*)(&Bs[p * KP + (ch << 3)]) = v;
  }
  if (threadIdx.x < 64) bfs[threadIdx.x] = bfin[(size_t)(m0 + threadIdx.x) * WIN + j];
  __syncthreads();
  int wv = threadIdx.x >> 6, lane = threadIdx.x & 63;
  int l15 = lane & 15, l4 = lane >> 4;
  f32x4 acc[4] = {};
#pragma unroll
  for (int t = 0; t < 4; ++t) {
    int col = (t << 5) + (l4 << 3);
    bf16x8 a = *(const bf16x8*)(&As[(wv * 16 + l15) * KP + col]);
#pragma unroll
    for (int q = 0; q < 4; ++q) {
      bf16x8 bb = *(const bf16x8*)(&Bs[(q * 16 + l15) * KP + col]);
      acc[q] = __builtin_amdgcn_mfma_f32_16x16x32_bf16(a, bb, acc[q], 0, 0, 0);
    }
  }
  // m_local = wv*16 + l4*4 + i  ->  half = wv>>1, g = (wv&1)*2 + (l4>>1),
  // m8 = (l4&1)*4. Stores hit 2x256B contiguous runs per wave instruction.
  size_t region = (size_t)((bid & 31) << 1) + (wv >> 1);
  int g = ((wv & 1) << 1) + (l4 >> 1);
  int m8 = (l4 & 1) << 2;
  int mb = wv * 16 + (l4 << 2);
#pragma unroll
  for (int q = 0; q < 4; ++q) {
    int p = q * 16 + l15;
    float z0 = acc[q][0] + bfs[mb + 0];
    float z1 = acc[q][1] + bfs[mb + 1];
    float z2 = acc[q][2] + bfs[mb + 2];
    float z3 = acc[q][3] + bfs[mb + 3];
    ushort4 st;
    st.x = f2bf(sigf(z0)); st.y = f2bf(sigf(z1));
    st.z = f2bf(sigf(z2)); st.w = f2bf(sigf(z3));
    *(ushort4*)(&Gt2[region * 67584 + ((size_t)(j * 4 + g) * 64 + p) * 8 + m8]) = st;
  }
}

// ------------- phase C: out[n,p] += sum_{j,m} xiT[n+j,m] * Gt2[j,p,m] ------
// R10: T4 counted-vmcnt barrier discipline (m201 two-barrier pattern).
// __syncthreads emits s_waitcnt vmcnt(0) before s_barrier (m97), so R5's
// "pipeline" drained the just-issued B(t+1) loads at every phase top —
// the staging latency was NEVER hidden. Now: raw s_barrier + counted
// vmcnt(cnt_{t+1}) via inline asm (never 0 mid-loop). Phase body:
//   issue B(t+1) -> SGB -> vmcnt(cnt_{t+1}) -> SGB -> s_barrier#1
//   -> ds_read+MFMA (compiler lgkmcnt) -> s_barrier#2
// Overwrite safety: buf[(t+1)&1]'s readers (phase t-1) passed barrier#2
// before phase t began. FIFO vmcnt: at the wait, outstanding = B(t)+B(t+1);
// vmcnt(cnt_{t+1}) drains exactly through B(t) (A(5)+B0(7) at t=0: wait 7).
// Data layout / swizzle / compute byte-identical to R5.
__global__ __launch_bounds__(256) void k_conv(const unsigned short* __restrict__ xiT,
                                              const unsigned short* __restrict__ Gt2,
                                              float* __restrict__ out) {
  extern __shared__ unsigned short lds[];
  unsigned short* As = lds;                // [160][64] swizzled = 20,480 B
  int bid = blockIdx.x;
  int mp = bid & 31;                       // bid%8 == mp%8 -> same-B blocks share an XCD
  int n0 = (bid >> 5) << 7;                // 16 n-tiles of 128
  int tid = threadIdx.x;
  int wv = tid >> 6, lane = tid & 63, l15 = lane & 15, l4 = lane >> 4;

  // ---- stage A once: contiguous 1KB per instr; XOR permute (c ^= row&7)
  const unsigned short* Abase = xiT + (size_t)mp * (NQ * 64) + (size_t)n0 * 64;
#pragma unroll
  for (int k = 0; k < 5; ++k) {
    int instr = wv * 5 + k;                // 5 VMEM per wave
    int s = (instr << 6) + lane;
    int row = s >> 3;
    int c = (s & 7) ^ (row & 7);
    gll16(Abase + (size_t)row * 64 + (c << 3), As + (instr << 9));
  }

  // phase tables: t = half*5 + p
  constexpr int JBT[10]  = {0, 7, 14, 21, 28, 0, 7, 14, 21, 28};
  constexpr int CNTT[10] = {7, 7, 7, 7, 5, 7, 7, 7, 7, 5};
  constexpr int HFT[10]  = {0, 0, 0, 0, 0, 1, 1, 1, 1, 1};

  const unsigned short* Rb0 = Gt2 + (size_t)(mp << 1) * 67584;        // half 0
  const unsigned short* Rb1 = Gt2 + (size_t)((mp << 1) + 1) * 67584;  // half 1

  // ---- prologue: issue B(phase 0) into buf0 (7 VMEM per wave)
  {
    const unsigned short* Bb = Rb0;        // jb=0
#pragma unroll
    for (int k = 0; k < 7; ++k) {
      int instr = wv * 7 + k;
      gll16(Bb + (((instr << 6) + lane) << 3), lds + 10240 + (instr << 9));
    }
  }

  f32x4 acc[2][4] = {};
#pragma unroll
  for (int t = 0; t < 10; ++t) {
    // ---- issue B(t+1) first (its buffer's readers finished at barrier#2
    //      of phase t-1); keeps cnt_{t+1} loads in flight across barrier#1
    if (t < 9) {
      const int jbn = JBT[t + 1], cntn = CNTT[t + 1];
      const unsigned short* Bb =
          (HFT[t + 1] ? Rb1 : Rb0) + ((size_t)jbn << 11);
      unsigned short* Bst = lds + 10240 + ((t + 1) & 1) * 14336;
#pragma unroll
      for (int k = 0; k < cntn; ++k) {
        int instr = wv * cntn + k;
        gll16(Bb + (((instr << 6) + lane) << 3), Bst + (instr << 9));
      }
    }
    __builtin_amdgcn_sched_barrier(0);
    // ---- counted wait: drain through B(t) (+A at t=0), keep B(t+1) in flight
    if (t == 9)               asm volatile("s_waitcnt vmcnt(0)");
    else if (CNTT[t + 1] == 7) asm volatile("s_waitcnt vmcnt(7)");
    else                       asm volatile("s_waitcnt vmcnt(5)");
    __builtin_amdgcn_sched_barrier(0);
    __builtin_amdgcn_s_barrier();          // #1: all waves' B(t) landed
    // ---- compute phase t from buf[t&1]
    {
      const int jb = JBT[t], cnt = CNTT[t], h4 = HFT[t] << 2;
      const unsigned short* Bs = lds + 10240 + (t & 1) * 14336;
      bf16x8 a[2], b[4];
#pragma unroll
      for (int s = 0; s < 2; ++s) {
        int row = wv * 32 + s * 16 + l15 + jb;
        a[s] = *(const bf16x8*)&As[row * 64 + (((h4 | l4) ^ (row & 7)) << 3)];
      }
#pragma unroll
      for (int q = 0; q < 4; ++q) {
        int slot = (l4 << 6) + (q << 4) + l15;
        b[q] = *(const bf16x8*)&Bs[slot << 3];
      }
#pragma unroll
      for (int jj = 0; jj < cnt; ++jj) {
        bf16x8 an[2], bn[4];
        if (jj < cnt - 1) {                // prefetch j+1 while computing j
#pragma unroll
          for (int s = 0; s < 2; ++s) {
            int row = wv * 32 + s * 16 + l15 + jb + jj + 1;
            an[s] = *(const bf16x8*)&As[row * 64 + (((h4 | l4) ^ (row & 7)) << 3)];
          }
#pragma unroll
          for (int q = 0; q < 4; ++q) {
            int slot = ((((jj + 1) << 2) + l4) << 6) + (q << 4) + l15;
            bn[q] = *(const bf16x8*)&Bs[slot << 3];
          }
        }
#pragma unroll
        for (int s = 0; s < 2; ++s)
#pragma unroll
          for (int q = 0; q < 4; ++q)
            acc[s][q] = __builtin_amdgcn_mfma_f32_16x16x32_bf16(a[s], b[q], acc[s][q], 0, 0, 0);
#pragma unroll
        for (int s = 0; s < 2; ++s) a[s] = an[s];
#pragma unroll
        for (int q = 0; q < 4; ++q) b[q] = bn[q];
      }
    }
    __builtin_amdgcn_s_barrier();          // #2: all waves done reading buf[t&1]
  }
#pragma unroll
  for (int s = 0; s < 2; ++s)
#pragma unroll
    for (int q = 0; q < 4; ++q) {
      int nr = n0 + wv * 32 + s * 16 + (l4 << 2);
      int p = q * 16 + l15;
#pragma unroll
      for (int i = 0; i < 4; ++i)
        atomicAdd(&out[(size_t)(nr + i) * MPTS + p], acc[s][q][i]);
    }
}

extern "C" void kernel_launch(void* const* d_in, const int* in_sizes, int n_in,
                              void* d_out, int out_size, void* d_ws, size_t ws_size,
                              hipStream_t stream) {
  const float* u    = (const float*)d_in[0];  // [64,64]
  const float* w0   = (const float*)d_in[1];  // [33,128,64]
  const float* b0   = (const float*)d_in[2];  // [33,128,1]
  const float* w    = (const float*)d_in[3];  // [2,33,128,128]
  const float* bias = (const float*)d_in[4];  // [2,33,128,1]
  const float* wf   = (const float*)d_in[5];  // [2048,33,128]
  const float* bfin = (const float*)d_in[6];  // [2048,33,1]
  const float* xi   = (const float*)d_in[7];  // [2048,2080]
  float* out = (float*)d_out;                 // [2048,64]
  char* ws = (char*)d_ws;
  unsigned short* xiT  = (unsigned short*)(ws);             // 8,519,680 B
  unsigned short* Gt2  = (unsigned short*)(ws + 8519680);   // 8,650,752 B
  unsigned short* u1bf = (unsigned short*)(ws + 17170432);  // 540,672 B

  hipFuncSetAttribute(reinterpret_cast<const void*>(&k_prep),
                      hipFuncAttributeMaxDynamicSharedMemorySize, 36352);
  hipFuncSetAttribute(reinterpret_cast<const void*>(&k_conv),
                      hipFuncAttributeMaxDynamicSharedMemorySize, 77824);

  k_prep<<<2113, 256, 36352, stream>>>(xi, xiT, u, w0, b0, w, bias, u1bf, out);
  k_final<<<33 * 32, 256, 0, stream>>>(wf, bfin, u1bf, Gt2);
  k_conv<<<512, 256, 77824, stream>>>(xiT, Gt2, out);
}